// Round 1
// baseline (715.827 us; speedup 1.0000x reference)
//
#include <hip/hip_runtime.h>
#include <hip/hip_cooperative_groups.h>
#include <math.h>

namespace cg = cooperative_groups;

#define NN      262144
#define WC      128
#define RR      4
#define OUTD    512
#define IFACED  919
#define CD      1431
#define C4      5724
#define PROJ_J  1157   // 512 out + 645 used iface entries
#define CMAX    2048   // candidate cap (E[n]=524 @ thr 2e-3)
#define NWAVE   4096   // NN/64 row-groups for softmax partial sums
#define ZCHW    45     // Wr k-chunks (32 rows each, last = 23)
#define ZCH     49     // + 4 chunks covering Wk's 128 rows
#define PKT     48     // proj k-chunks of 30

// workspace layout (4-byte words)
#define OFF_CCNT    8          // u32[1]
#define OFF_XW      16         // f32[128]
#define OFF_H       160        // f32[1431]
#define OFF_C       1600       // f32[1431]
#define OFF_Z0      3040       // f32[5724]
#define OFF_Z1      8768       // f32[5724]
#define OFF_IFC     14496      // f32[919]  iface atomic accumulator
#define OFF_CAND    15416      // u64[2048] (even word offset -> 8B aligned)
#define OFF_PSUM    19512      // f32[4096*5]
#define OFF_SCORES  40000      // f32[5*N]

__device__ __forceinline__ float sigm(float x) { return 1.f / (1.f + expf(-x)); }
__device__ __forceinline__ float softplusf(float x) { return x > 20.f ? x : log1pf(expf(x)); }

__global__ __launch_bounds__(512, 4) void k_fused(
    const float* __restrict__ x,  const float* __restrict__ dk,
    const float* __restrict__ db, const float* __restrict__ lk,
    const float* __restrict__ lr, const float* __restrict__ lb,
    const float* __restrict__ h0, const float* __restrict__ c0,
    const float* __restrict__ rv, const float* __restrict__ Wo,
    const float* __restrict__ Wi, const float* __restrict__ M,
    const float* __restrict__ us, float* __restrict__ out,
    float* __restrict__ ws)
{
  cg::grid_group grid = cg::this_grid();
  const int T   = gridDim.x * blockDim.x;
  const int tid = blockIdx.x * blockDim.x + threadIdx.x;

  float* hbuf   = ws + OFF_H;
  float* cbuf   = ws + OFF_C;
  float* xw     = ws + OFF_XW;
  float* ifc    = ws + OFF_IFC;
  float* psums  = ws + OFF_PSUM;
  float* scores = ws + OFF_SCORES;
  unsigned* ccnt = (unsigned*)(ws + OFF_CCNT);
  unsigned long long* cand = (unsigned long long*)(ws + OFF_CAND);

  __shared__ float sxw[512];
  __shared__ float s_rk[RR * WC];
  __shared__ float s_wk[WC];
  __shared__ float sred[8][5];
  __shared__ float ssum[5];
  __shared__ unsigned long long sc[CMAX];
  __shared__ unsigned long long srt[CMAX];
  __shared__ float cpe[200];

  // ---------------- P0: init h/c, z0 = bias, zero accumulators; block0: xw ----
  for (int t = tid; t < CD; t += T) { hbuf[t] = h0[t]; cbuf[t] = c0[t]; }
  for (int q = tid; q < C4; q += T) ws[OFF_Z0 + q] = lb[q];
  for (int q = tid; q < OUTD; q += T) out[q] = 0.f;
  for (int q = tid; q < IFACED; q += T) ifc[q] = 0.f;
  if (tid == 0) *ccnt = 0u;
  if (blockIdx.x == 0) {
    int t = threadIdx.x;
    int j = t & (WC - 1), kt = t >> 7;          // 4 k-chunks x 128
    const float* col = dk + j;
    float acc = 0.f;
    int k0 = kt * 128;
    #pragma unroll 8
    for (int k = k0; k < k0 + 128; ++k) acc = fmaf(x[k], col[(size_t)k * WC], acc);
    sxw[t] = acc;
    __syncthreads();
    if (t < WC) xw[t] = db[t] + sxw[t] + sxw[t + 128] + sxw[t + 256] + sxw[t + 384];
  }
  grid.sync();

  // ---------------- LSTM: 5 steps, split-K matvec (atomic) + gates ----------
  for (int step = 0; step < 5; ++step) {
    const float* xt = (step == 0) ? xw : (rv + (step - 1) * WC);
    float* zcur  = ws + ((step & 1) ? OFF_Z1 : OFF_Z0);
    float* znext = ws + ((step & 1) ? OFF_Z0 : OFF_Z1);

    for (int task = tid; task < ZCH * C4; task += T) {
      int ch = task / C4;
      int j  = task - ch * C4;
      float acc = 0.f;
      if (ch < ZCHW) {
        int k0 = ch * 32, k1 = (ch == ZCHW - 1) ? CD : k0 + 32;
        const float* col = lr + j;
        #pragma unroll 8
        for (int k = k0; k < k1; ++k) acc = fmaf(hbuf[k], col[(size_t)k * C4], acc);
      } else {
        int k0 = (ch - ZCHW) * 32;
        const float* col = lk + j;
        #pragma unroll 8
        for (int k = k0; k < k0 + 32; ++k) acc = fmaf(xt[k], col[(size_t)k * C4], acc);
      }
      atomicAdd(&zcur[j], acc);
    }
    grid.sync();

    for (int q = tid; q < C4; q += T) znext[q] = lb[q];   // pre-init next z
    for (int j = tid; j < CD; j += T) {
      float zi = zcur[j], zf = zcur[CD + j], zg = zcur[2 * CD + j], zo = zcur[3 * CD + j];
      float cn = sigm(zf) * cbuf[j] + sigm(zi) * tanhf(zg);
      cbuf[j] = cn;
      hbuf[j] = sigm(zo) * tanhf(cn);
    }
    grid.sync();
  }

  // ---------------- projection: split-K atomicAdd into out[0:512] + ifc -----
  for (int task = tid; task < PKT * PROJ_J; task += T) {
    int kt = task / PROJ_J;
    int j  = task - kt * PROJ_J;
    const float* col; int stride; float* dst;
    if (j < OUTD) { col = Wo + j; stride = OUTD; dst = out + j; }
    else { col = Wi + (j - OUTD); stride = IFACED; dst = ifc + (j - OUTD); }
    int k0 = kt * 30, k1 = k0 + 30; if (k1 > CD) k1 = CD;
    float acc = 0.f;
    #pragma unroll 6
    for (int k = k0; k < k1; ++k) acc = fmaf(hbuf[k], col[(size_t)k * stride], acc);
    atomicAdd(dst, acc);
  }
  grid.sync();

  // ---------------- key normalization: every block, into its own LDS --------
  {
    int t = threadIdx.x;
    if (t < 320) {
      int w = t >> 6, lane = t & 63;
      float beta = 1.f + softplusf((w < 4) ? ifc[RR * WC + w] : ifc[RR * WC + RR + WC]);
      const float* src = (w < 4) ? (ifc + w * WC) : (ifc + RR * WC + RR);
      float v0 = src[lane], v1 = src[lane + 64];
      float ssq = v0 * v0 + v1 * v1;
      for (int off = 1; off < 64; off <<= 1) ssq += __shfl_xor(ssq, off);
      float rn = rsqrtf(fmaxf(ssq, 1e-12f)) * beta;
      float* dstp = (w < 4) ? (s_rk + w * WC) : s_wk;
      dstp[lane] = v0 * rn; dstp[lane + 64] = v1 * rn;
    }
    __syncthreads();
  }

  // ---------------- scores: one row per thread, keys from LDS ---------------
  {
    const float4* K0 = (const float4*)(s_rk);
    const float4* K1 = (const float4*)(s_rk + WC);
    const float4* K2 = (const float4*)(s_rk + 2 * WC);
    const float4* K3 = (const float4*)(s_rk + 3 * WC);
    const float4* KW = (const float4*)(s_wk);
    for (int i = tid; i < NN; i += T) {
      const float4* rowp = (const float4*)(M + (size_t)i * WC);
      float a0 = 0, a1 = 0, a2 = 0, a3 = 0, a4 = 0, ssq = 0;
      #pragma unroll 4
      for (int k = 0; k < 32; ++k) {
        float4 m = rowp[k];
        float4 c0v = K0[k], c1v = K1[k], c2v = K2[k], c3v = K3[k], cwv = KW[k];
        ssq = fmaf(m.x, m.x, fmaf(m.y, m.y, fmaf(m.z, m.z, fmaf(m.w, m.w, ssq))));
        a0 = fmaf(m.x, c0v.x, fmaf(m.y, c0v.y, fmaf(m.z, c0v.z, fmaf(m.w, c0v.w, a0))));
        a1 = fmaf(m.x, c1v.x, fmaf(m.y, c1v.y, fmaf(m.z, c1v.z, fmaf(m.w, c1v.w, a1))));
        a2 = fmaf(m.x, c2v.x, fmaf(m.y, c2v.y, fmaf(m.z, c2v.z, fmaf(m.w, c2v.w, a2))));
        a3 = fmaf(m.x, c3v.x, fmaf(m.y, c3v.y, fmaf(m.z, c3v.z, fmaf(m.w, c3v.w, a3))));
        a4 = fmaf(m.x, cwv.x, fmaf(m.y, cwv.y, fmaf(m.z, cwv.z, fmaf(m.w, cwv.w, a4))));
      }
      float rn = rsqrtf(fmaxf(ssq, 1e-12f));
      float e0 = expf(a0 * rn), e1 = expf(a1 * rn), e2 = expf(a2 * rn),
            e3 = expf(a3 * rn), e4 = expf(a4 * rn);
      scores[0 * (size_t)NN + i] = e0;
      scores[1 * (size_t)NN + i] = e1;
      scores[2 * (size_t)NN + i] = e2;
      scores[3 * (size_t)NN + i] = e3;
      scores[4 * (size_t)NN + i] = e4;
      for (int off = 1; off < 64; off <<= 1) {
        e0 += __shfl_xor(e0, off); e1 += __shfl_xor(e1, off); e2 += __shfl_xor(e2, off);
        e3 += __shfl_xor(e3, off); e4 += __shfl_xor(e4, off);
      }
      if ((threadIdx.x & 63) == 0) {
        float* pp = psums + (i >> 6) * 5;
        pp[0] = e0; pp[1] = e1; pp[2] = e2; pp[3] = e3; pp[4] = e4;
      }
    }
  }
  grid.sync();

  // ---------------- per-block psum reduce (redundant) + tail ----------------
  {
    float p0 = 0, p1 = 0, p2 = 0, p3 = 0, p4 = 0;
    for (int k = threadIdx.x; k < NWAVE; k += blockDim.x) {
      const float* pp = psums + k * 5;
      p0 += pp[0]; p1 += pp[1]; p2 += pp[2]; p3 += pp[3]; p4 += pp[4];
    }
    for (int off = 1; off < 64; off <<= 1) {
      p0 += __shfl_xor(p0, off); p1 += __shfl_xor(p1, off); p2 += __shfl_xor(p2, off);
      p3 += __shfl_xor(p3, off); p4 += __shfl_xor(p4, off);
    }
    int wv = threadIdx.x >> 6, ln = threadIdx.x & 63;
    if (ln == 0) { sred[wv][0] = p0; sred[wv][1] = p1; sred[wv][2] = p2; sred[wv][3] = p3; sred[wv][4] = p4; }
    __syncthreads();
    if (threadIdx.x < 5) {
      float s = 0.f;
      for (int q = 0; q < 8; ++q) s += sred[q][threadIdx.x];
      ssum[threadIdx.x] = s;
    }
    __syncthreads();
  }
  {
    float i0 = 1.f / ssum[0], i1 = 1.f / ssum[1], i2 = 1.f / ssum[2],
          i3 = 1.f / ssum[3], i4 = 1.f / ssum[4];
    for (int i = tid; i < NN; i += T) {
      float4 wr;
      wr.x = scores[0 * (size_t)NN + i] * i0;
      wr.y = scores[1 * (size_t)NN + i] * i1;
      wr.z = scores[2 * (size_t)NN + i] * i2;
      wr.w = scores[3 * (size_t)NN + i] * i3;
      *(float4*)(out + OUTD + (size_t)i * 4) = wr;
      out[OUTD + 4 * (size_t)NN + i] = scores[4 * (size_t)NN + i] * i4;
      out[OUTD + 5 * (size_t)NN + i] = 0.f;   // alloc zero-fill; overwritten below
      float u = us[i];
      if (u < 2e-3f) {
        unsigned slot = atomicAdd(ccnt, 1u);
        if (slot < CMAX) cand[slot] = ((unsigned long long)__float_as_uint(u) << 32) | (unsigned)i;
      }
    }
  }
  grid.sync();

  // ---------------- alloc: block 0, exact rank-sort + fp32 cumprod ----------
  // cumprod of sorted ascending uniforms underflows (<1e-38) after ~10 terms;
  // ranks >= 200 keep the zero from the tail phase (ref values there < 1e-38).
  if (blockIdx.x == 0) {
    int n = (int)*ccnt; if (n > CMAX) n = CMAX;
    for (int t = threadIdx.x; t < n; t += blockDim.x) sc[t] = cand[t];
    __syncthreads();
    for (int t = threadIdx.x; t < n; t += blockDim.x) {
      unsigned long long v = sc[t];
      int r = 0;
      for (int j2 = 0; j2 < n; ++j2) r += (sc[j2] < v);
      srt[r] = v;
    }
    __syncthreads();
    int lim = n < 200 ? n : 200;
    if (threadIdx.x == 0) {
      float cp = 1.f;
      for (int r = 0; r < lim; ++r) {
        cpe[r] = cp;
        cp *= __uint_as_float((unsigned)(srt[r] >> 32));
      }
    }
    __syncthreads();
    for (int r = threadIdx.x; r < lim; r += blockDim.x) {
      unsigned long long p = srt[r];
      float s = __uint_as_float((unsigned)(p >> 32));
      out[OUTD + 5 * (size_t)NN + (unsigned)p] = (1.f - s) * cpe[r];
    }
  }
}

extern "C" void kernel_launch(void* const* d_in, const int* in_sizes, int n_in,
                              void* d_out, int out_size, void* d_ws, size_t ws_size,
                              hipStream_t stream) {
  const float* x  = (const float*)d_in[0];
  const float* dk = (const float*)d_in[1];
  const float* db = (const float*)d_in[2];
  const float* lk = (const float*)d_in[3];
  const float* lr = (const float*)d_in[4];
  const float* lb = (const float*)d_in[5];
  const float* h0 = (const float*)d_in[6];
  const float* c0 = (const float*)d_in[7];
  const float* rv = (const float*)d_in[8];
  const float* Wo = (const float*)d_in[9];
  const float* Wi = (const float*)d_in[10];
  const float* M  = (const float*)d_in[11];
  const float* us = (const float*)d_in[12];
  float* out = (float*)d_out;
  float* ws  = (float*)d_ws;

  // one-time: clamp grid to cooperative co-residency (all phases grid-stride)
  static int grid = 0;
  if (grid == 0) {
    int nb = 0;
    if (hipOccupancyMaxActiveBlocksPerMultiprocessor(&nb, (const void*)k_fused, 512, 0) != hipSuccess || nb < 1)
      nb = 1;
    int g = nb * 256;               // 256 CUs on MI355X
    grid = g < 512 ? g : 512;       // want 512 blocks x 512 thr = 1 thread/row
  }

  void* args[] = { &x, &dk, &db, &lk, &lr, &lb, &h0, &c0, &rv,
                   &Wo, &Wi, &M, &us, &out, &ws };
  hipLaunchCooperativeKernel((const void*)k_fused, dim3(grid), dim3(512),
                             args, 0, stream);
}

// Round 3
// 433.398 us; speedup vs baseline: 1.6517x; 1.6517x over previous
//
#include <hip/hip_runtime.h>
#include <math.h>

#define NN      262144
#define WC      128
#define RR      4
#define OUTD    512
#define IFACED  919
#define CD      1431
#define C4      5724
#define PROJ_J  1157   // 512 out + 645 used iface entries
#define CMAX    2048   // candidate cap (E[n]=524 @ thr 2e-3)
#define ZCHW    45     // Wr k-chunks (32 rows, last=23)
#define ZCH     49     // + 4 chunks covering Wk's 128 rows
#define PKT     48     // proj k-chunks of 30

// ---- ws word offsets. [0 .. WS_ZERO_WORDS) zeroed by k_init pre-launch.
#define OFF_BAR     0                    // u32 barrier counter (monotonic)
#define OFF_CCNT    8                    // u32 candidate count
#define OFF_Z       16                   // f32[5][C4] per-step z accumulators
#define OFF_IFC     (OFF_Z + 5*C4)       // 28636: f32[919] iface accumulator
#define OFF_PO      (OFF_IFC + 920)      // 29556: f32[512] out-proj accumulator
#define WS_ZERO_WORDS (OFF_PO + OUTD)    // 30068
#define OFF_BSUM    30080                // f32[grid*5] per-block softmax sums
#define OFF_CAND    32768                // u64[2048] (8B aligned)
#define OFF_SCORES  36864                // f32[5*NN] (same-thread store/reload)

__device__ __forceinline__ float sigm(float x) { return 1.f / (1.f + expf(-x)); }
__device__ __forceinline__ float softplusf(float x) { return x > 20.f ? x : log1pf(expf(x)); }

// agent-scope (device-coherent, L3) accessors — no L2 flush needed anywhere
__device__ __forceinline__ float gldf(const float* p) {
  return __hip_atomic_load(p, __ATOMIC_RELAXED, __HIP_MEMORY_SCOPE_AGENT);
}
__device__ __forceinline__ void gstf(float* p, float v) {
  __hip_atomic_store(p, v, __ATOMIC_RELAXED, __HIP_MEMORY_SCOPE_AGENT);
}
__device__ __forceinline__ unsigned gldu(const unsigned* p) {
  return __hip_atomic_load(p, __ATOMIC_RELAXED, __HIP_MEMORY_SCOPE_AGENT);
}
__device__ __forceinline__ unsigned long long gldu64(const unsigned long long* p) {
  return __hip_atomic_load(p, __ATOMIC_RELAXED, __HIP_MEMORY_SCOPE_AGENT);
}
__device__ __forceinline__ void gstu64(unsigned long long* p, unsigned long long v) {
  __hip_atomic_store(p, v, __ATOMIC_RELAXED, __HIP_MEMORY_SCOPE_AGENT);
}

// ---- init: zero barrier/ccnt/z/ifc/po (plain launch — proven capture-safe)
__global__ void k_init(float* __restrict__ ws) {
  int t = blockIdx.x * 1024 + threadIdx.x;
  if (t < WS_ZERO_WORDS) ws[t] = 0.f;
}

// ---- lightweight grid barrier: monotonic counter, relaxed agent atomics.
// Correct because data crossing the barrier is written agent-scope / via
// device-scope atomics (at the coherent point once vmcnt drains) and read
// agent-scope (bypasses stale L1/L2). No L2 writeback/invalidate anywhere.
__device__ __forceinline__ void gbar(unsigned* bar, unsigned target) {
  asm volatile("s_waitcnt vmcnt(0) lgkmcnt(0)" ::: "memory");  // drain this wave's stores
  __syncthreads();                                             // all waves of block drained
  if (threadIdx.x == 0) {
    __hip_atomic_fetch_add(bar, 1u, __ATOMIC_RELAXED, __HIP_MEMORY_SCOPE_AGENT);
    while (__hip_atomic_load(bar, __ATOMIC_RELAXED, __HIP_MEMORY_SCOPE_AGENT) < target)
      __builtin_amdgcn_s_sleep(1);
  }
  __syncthreads();
}

__global__ __launch_bounds__(512, 4) void k_fused(
    const float* __restrict__ x,  const float* __restrict__ dk,
    const float* __restrict__ db, const float* __restrict__ lk,
    const float* __restrict__ lr, const float* __restrict__ lb,
    const float* __restrict__ h0, const float* __restrict__ c0,
    const float* __restrict__ rv, const float* __restrict__ Wo,
    const float* __restrict__ Wi, const float* __restrict__ M,
    const float* __restrict__ us, float* __restrict__ out,
    float* __restrict__ ws)
{
  const unsigned T   = gridDim.x * blockDim.x;
  const unsigned tid = blockIdx.x * blockDim.x + threadIdx.x;
  unsigned* bar  = (unsigned*)(ws + OFF_BAR);
  unsigned* ccnt = (unsigned*)(ws + OFF_CCNT);
  float* ifc     = ws + OFF_IFC;
  float* po      = ws + OFF_PO;
  float* bsum    = ws + OFF_BSUM;
  float* scores  = ws + OFF_SCORES;
  unsigned long long* cand = (unsigned long long*)(ws + OFF_CAND);
  unsigned ep = 0;

  __shared__ float sh[CD];          // h, per-block replica
  __shared__ float scc[CD];         // c, per-block replica
  __shared__ float sxw[512];        // xw partials, then xw in [0:128)
  __shared__ float s_rk[RR * WC];
  __shared__ float s_wk[WC];
  __shared__ float swred[8][5];
  __shared__ float ssum[5];
  __shared__ unsigned long long sc[CMAX];
  __shared__ unsigned long long srt[CMAX];
  __shared__ float cpe[200];

  // ---- init: h0/c0 -> LDS; xw = x@dense+bias computed redundantly per block
  for (int t = threadIdx.x; t < CD; t += 512) { sh[t] = h0[t]; scc[t] = c0[t]; }
  {
    int j = threadIdx.x & (WC - 1), kc = threadIdx.x >> 7;   // 4 k-chunks x 128
    const float* col = dk + j;
    float a = 0.f;
    int k0 = kc * 128;
    #pragma unroll 8
    for (int k = k0; k < k0 + 128; ++k) a = fmaf(x[k], col[(size_t)k * WC], a);
    sxw[threadIdx.x] = a;
  }
  __syncthreads();
  {
    float v = 0.f;
    if (threadIdx.x < WC)
      v = db[threadIdx.x] + sxw[threadIdx.x] + sxw[threadIdx.x + 128] +
          sxw[threadIdx.x + 256] + sxw[threadIdx.x + 384];
    __syncthreads();
    if (threadIdx.x < WC) sxw[threadIdx.x] = v;
    __syncthreads();
  }

  // ---- LSTM: 5 steps. One barrier per step; gates redundant per block. -----
  // z_s buffers pre-zeroed by k_init; bias folded into gates.
  for (int step = 0; step < 5; ++step) {
    float* zs = ws + OFF_Z + step * C4;
    for (unsigned task = tid; task < (unsigned)(ZCH * C4); task += T) {
      int ch = task / C4;
      int j  = task - ch * C4;
      float acc = 0.f;
      if (ch < ZCHW) {
        int k0 = ch * 32, k1 = (ch == ZCHW - 1) ? CD : k0 + 32;
        const float* col = lr + j;
        #pragma unroll 8
        for (int k = k0; k < k1; ++k) acc = fmaf(sh[k], col[(size_t)k * C4], acc);
      } else {
        int k0 = (ch - ZCHW) * 32;
        const float* col = lk + j;
        if (step == 0) {
          #pragma unroll 8
          for (int k = k0; k < k0 + 32; ++k) acc = fmaf(sxw[k], col[(size_t)k * C4], acc);
        } else {
          const float* xt = rv + (step - 1) * WC;
          #pragma unroll 8
          for (int k = k0; k < k0 + 32; ++k) acc = fmaf(xt[k], col[(size_t)k * C4], acc);
        }
      }
      atomicAdd(&zs[j], acc);   // device-scope: lands at coherent point
    }
    ++ep; gbar(bar, ep * gridDim.x);
    // gates: every block redundantly, z via agent loads, h/c stay in LDS
    for (int j = threadIdx.x; j < CD; j += 512) {
      float zi = gldf(zs + j)          + lb[j];
      float zf = gldf(zs + CD + j)     + lb[CD + j];
      float zg = gldf(zs + 2 * CD + j) + lb[2 * CD + j];
      float zo = gldf(zs + 3 * CD + j) + lb[3 * CD + j];
      float cn = sigm(zf) * scc[j] + sigm(zi) * tanhf(zg);
      scc[j] = cn;
      sh[j]  = sigm(zo) * tanhf(cn);
    }
    __syncthreads();
  }

  // ---- projection: split-K, atomicAdd into po (out) / ifc ------------------
  for (unsigned task = tid; task < (unsigned)(PKT * PROJ_J); task += T) {
    int kt = task / PROJ_J;
    int j  = task - kt * PROJ_J;
    const float* col; int stride; float* dst;
    if (j < OUTD) { col = Wo + j; stride = OUTD; dst = po + j; }
    else { col = Wi + (j - OUTD); stride = IFACED; dst = ifc + (j - OUTD); }
    int k0 = kt * 30, k1 = k0 + 30; if (k1 > CD) k1 = CD;
    float acc = 0.f;
    #pragma unroll 6
    for (int k = k0; k < k1; ++k) acc = fmaf(sh[k], col[(size_t)k * stride], acc);
    atomicAdd(dst, acc);
  }
  ++ep; gbar(bar, ep * gridDim.x);

  // ---- block 0 copies po -> out[0:512]; all blocks normalize keys ----------
  if (blockIdx.x == 0) out[threadIdx.x] = gldf(po + threadIdx.x);
  if (threadIdx.x < 320) {
    int w = threadIdx.x >> 6, lane = threadIdx.x & 63;
    float beta = 1.f + softplusf((w < 4) ? gldf(ifc + RR * WC + w)
                                         : gldf(ifc + RR * WC + RR + WC));
    const float* src = (w < 4) ? (ifc + w * WC) : (ifc + RR * WC + RR);
    float v0 = gldf(src + lane), v1 = gldf(src + lane + 64);
    float sq = v0 * v0 + v1 * v1;
    for (int off = 1; off < 64; off <<= 1) sq += __shfl_xor(sq, off);
    float rn = rsqrtf(fmaxf(sq, 1e-12f)) * beta;
    float* dstp = (w < 4) ? (s_rk + w * WC) : s_wk;
    dstp[lane] = v0 * rn; dstp[lane + 64] = v1 * rn;
  }
  __syncthreads();

  // ---- scores: one row per thread, keys from LDS; block partial sums -------
  float p0 = 0, p1 = 0, p2 = 0, p3 = 0, p4 = 0;
  {
    const float4* K0 = (const float4*)(s_rk);
    const float4* K1 = (const float4*)(s_rk + WC);
    const float4* K2 = (const float4*)(s_rk + 2 * WC);
    const float4* K3 = (const float4*)(s_rk + 3 * WC);
    const float4* KW = (const float4*)(s_wk);
    for (unsigned i = tid; i < NN; i += T) {
      const float4* rowp = (const float4*)(M + (size_t)i * WC);
      float a0 = 0, a1 = 0, a2 = 0, a3 = 0, a4 = 0, sq = 0;
      #pragma unroll 4
      for (int k = 0; k < 32; ++k) {
        float4 m = rowp[k];
        float4 c0v = K0[k], c1v = K1[k], c2v = K2[k], c3v = K3[k], cwv = KW[k];
        sq = fmaf(m.x, m.x, fmaf(m.y, m.y, fmaf(m.z, m.z, fmaf(m.w, m.w, sq))));
        a0 = fmaf(m.x, c0v.x, fmaf(m.y, c0v.y, fmaf(m.z, c0v.z, fmaf(m.w, c0v.w, a0))));
        a1 = fmaf(m.x, c1v.x, fmaf(m.y, c1v.y, fmaf(m.z, c1v.z, fmaf(m.w, c1v.w, a1))));
        a2 = fmaf(m.x, c2v.x, fmaf(m.y, c2v.y, fmaf(m.z, c2v.z, fmaf(m.w, c2v.w, a2))));
        a3 = fmaf(m.x, c3v.x, fmaf(m.y, c3v.y, fmaf(m.z, c3v.z, fmaf(m.w, c3v.w, a3))));
        a4 = fmaf(m.x, cwv.x, fmaf(m.y, cwv.y, fmaf(m.z, cwv.z, fmaf(m.w, cwv.w, a4))));
      }
      float rn = rsqrtf(fmaxf(sq, 1e-12f));
      float e0 = expf(a0 * rn), e1 = expf(a1 * rn), e2 = expf(a2 * rn),
            e3 = expf(a3 * rn), e4 = expf(a4 * rn);
      // plain stores: re-read by the SAME thread after the barrier (same XCD)
      scores[0 * (size_t)NN + i] = e0;
      scores[1 * (size_t)NN + i] = e1;
      scores[2 * (size_t)NN + i] = e2;
      scores[3 * (size_t)NN + i] = e3;
      scores[4 * (size_t)NN + i] = e4;
      p0 += e0; p1 += e1; p2 += e2; p3 += e3; p4 += e4;
    }
  }
  {
    for (int off = 1; off < 64; off <<= 1) {
      p0 += __shfl_xor(p0, off); p1 += __shfl_xor(p1, off); p2 += __shfl_xor(p2, off);
      p3 += __shfl_xor(p3, off); p4 += __shfl_xor(p4, off);
    }
    int wv = threadIdx.x >> 6, ln = threadIdx.x & 63;
    if (ln == 0) { swred[wv][0] = p0; swred[wv][1] = p1; swred[wv][2] = p2;
                   swred[wv][3] = p3; swred[wv][4] = p4; }
    __syncthreads();
    if (threadIdx.x < 5) {
      float s = 0.f;
      for (int q = 0; q < 8; ++q) s += swred[q][threadIdx.x];
      gstf(bsum + blockIdx.x * 5 + threadIdx.x, s);
    }
  }
  ++ep; gbar(bar, ep * gridDim.x);

  // ---- totals (redundant per block) + finalize outputs + candidate filter --
  {
    float q0 = 0, q1 = 0, q2 = 0, q3 = 0, q4 = 0;
    for (unsigned t = threadIdx.x; t < gridDim.x; t += 512) {
      const float* bp = bsum + t * 5;
      q0 += gldf(bp); q1 += gldf(bp + 1); q2 += gldf(bp + 2);
      q3 += gldf(bp + 3); q4 += gldf(bp + 4);
    }
    for (int off = 1; off < 64; off <<= 1) {
      q0 += __shfl_xor(q0, off); q1 += __shfl_xor(q1, off); q2 += __shfl_xor(q2, off);
      q3 += __shfl_xor(q3, off); q4 += __shfl_xor(q4, off);
    }
    int wv = threadIdx.x >> 6, ln = threadIdx.x & 63;
    if (ln == 0) { swred[wv][0] = q0; swred[wv][1] = q1; swred[wv][2] = q2;
                   swred[wv][3] = q3; swred[wv][4] = q4; }
    __syncthreads();
    if (threadIdx.x < 5) {
      float s = 0.f;
      for (int q = 0; q < 8; ++q) s += swred[q][threadIdx.x];
      ssum[threadIdx.x] = s;
    }
    __syncthreads();
  }
  {
    float i0 = 1.f / ssum[0], i1 = 1.f / ssum[1], i2 = 1.f / ssum[2],
          i3 = 1.f / ssum[3], i4 = 1.f / ssum[4];
    for (unsigned i = tid; i < NN; i += T) {
      float4 wr;
      wr.x = scores[0 * (size_t)NN + i] * i0;
      wr.y = scores[1 * (size_t)NN + i] * i1;
      wr.z = scores[2 * (size_t)NN + i] * i2;
      wr.w = scores[3 * (size_t)NN + i] * i3;
      *(float4*)(out + OUTD + (size_t)i * 4) = wr;                  // single writer
      out[OUTD + 4 * (size_t)NN + i] = scores[4 * (size_t)NN + i] * i4;
      gstf(out + OUTD + 5 * (size_t)NN + i, 0.f);  // alloc col agent-scope (no dirty L2)
      float u = us[i];
      if (u < 2e-3f) {
        unsigned slot = atomicAdd(ccnt, 1u);
        if (slot < CMAX)
          gstu64(cand + slot, ((unsigned long long)__float_as_uint(u) << 32) | i);
      }
    }
  }
  ++ep; gbar(bar, ep * gridDim.x);

  // ---- alloc: block 0, exact rank-sort of candidates + fp32 cumprod --------
  // cumprod of sorted ascending uniforms underflows after ~10 terms; ranks>=200
  // keep the zero written above (ref values there < 1e-38). Composite keys
  // (u<<32)|i are unique -> ranks are a permutation.
  if (blockIdx.x == 0) {
    int n = (int)gldu(ccnt); if (n > CMAX) n = CMAX;
    for (int t = threadIdx.x; t < n; t += 512) sc[t] = gldu64(cand + t);
    __syncthreads();
    for (int t = threadIdx.x; t < n; t += 512) {
      unsigned long long v = sc[t];
      int r = 0;
      for (int j2 = 0; j2 < n; ++j2) r += (sc[j2] < v);
      srt[r] = v;
    }
    __syncthreads();
    int lim = n < 200 ? n : 200;
    if (threadIdx.x == 0) {
      float cp = 1.f;
      for (int r = 0; r < lim; ++r) {
        cpe[r] = cp;
        cp *= __uint_as_float((unsigned)(srt[r] >> 32));
      }
    }
    __syncthreads();
    for (int r = threadIdx.x; r < lim; r += 512) {
      unsigned long long pr = srt[r];
      float s = __uint_as_float((unsigned)(pr >> 32));
      gstf(out + OUTD + 5 * (size_t)NN + (unsigned)pr, (1.f - s) * cpe[r]);
    }
  }
}

extern "C" void kernel_launch(void* const* d_in, const int* in_sizes, int n_in,
                              void* d_out, int out_size, void* d_ws, size_t ws_size,
                              hipStream_t stream) {
  const float* x  = (const float*)d_in[0];
  const float* dk = (const float*)d_in[1];
  const float* db = (const float*)d_in[2];
  const float* lk = (const float*)d_in[3];
  const float* lr = (const float*)d_in[4];
  const float* lb = (const float*)d_in[5];
  const float* h0 = (const float*)d_in[6];
  const float* c0 = (const float*)d_in[7];
  const float* rv = (const float*)d_in[8];
  const float* Wo = (const float*)d_in[9];
  const float* Wi = (const float*)d_in[10];
  const float* M  = (const float*)d_in[11];
  const float* us = (const float*)d_in[12];
  float* out = (float*)d_out;
  float* ws  = (float*)d_ws;

  static int grid = 0;
  if (grid == 0) {
    int nb = 0;
    if (hipOccupancyMaxActiveBlocksPerMultiprocessor(&nb, (const void*)k_fused, 512, 0) != hipSuccess || nb < 1)
      nb = 1;
    long g = (long)nb * 256;        // 256 CUs
    grid = (int)(g < 512 ? g : 512);
  }

  // zero barrier counter, ccnt, z[5], ifc, po — plain kernel, capture-safe
  k_init<<<(WS_ZERO_WORDS + 1023) / 1024, 1024, 0, stream>>>(ws);

  void* args[] = { &x, &dk, &db, &lk, &lr, &lb, &h0, &c0, &rv,
                   &Wo, &Wi, &M, &us, &out, &ws };
  hipLaunchCooperativeKernel((const void*)k_fused, dim3(grid), dim3(512),
                             args, 0, stream);
}

// Round 4
// 380.356 us; speedup vs baseline: 1.8820x; 1.1395x over previous
//
#include <hip/hip_runtime.h>
#include <math.h>

#define NN      262144
#define WC      128
#define RR      4
#define OUTD    512
#define IFACED  919
#define CD      1431
#define C4      5724
#define PROJ_J  1157   // 512 out + 645 used iface entries
#define CMAX    2048   // candidate cap (E[n]=524 @ thr 2e-3)
#define ZCHW    45     // Wr k-chunks (32 rows, last=23)
#define ZCH     49     // + 4 chunks covering Wk's 128 rows
#define PKT     48     // proj k-chunks of 30

// ---- ws word offsets. [0 .. WS_ZERO_WORDS) zeroed by k_init pre-launch.
#define OFF_BARS    0                    // u32[8] arrival counters, 128B apart (words 0,32,...,224)
#define OFF_REL     256                  // u32 release epoch (own cache line)
#define OFF_CCNT    288                  // u32 candidate count (own line)
#define OFF_Z       320                  // f32[5][C4] per-step z accumulators
#define OFF_IFC     (OFF_Z + 5*C4)       // 28940: f32[919] iface accumulator
#define OFF_PO      (OFF_IFC + 920)      // 29860: f32[512] out-proj accumulator
#define WS_ZERO_WORDS (OFF_PO + OUTD)    // 30372
#define OFF_BSUM    30464                // f32[grid*5] per-block softmax sums
#define OFF_CAND    33024                // u64[2048] (8B aligned)
#define OFF_SCORES  37120                // f32[5*NN] (same-thread store/reload)

__device__ __forceinline__ float sigm(float x) { return 1.f / (1.f + expf(-x)); }
__device__ __forceinline__ float softplusf(float x) { return x > 20.f ? x : log1pf(expf(x)); }

// agent-scope (device-coherent) accessors — performed at the coherent point,
// bypassing stale per-XCD L2s. No L2 writeback/invalidate anywhere.
__device__ __forceinline__ float gldf(const float* p) {
  return __hip_atomic_load(p, __ATOMIC_RELAXED, __HIP_MEMORY_SCOPE_AGENT);
}
__device__ __forceinline__ void gstf(float* p, float v) {
  __hip_atomic_store(p, v, __ATOMIC_RELAXED, __HIP_MEMORY_SCOPE_AGENT);
}
__device__ __forceinline__ unsigned gldu(const unsigned* p) {
  return __hip_atomic_load(p, __ATOMIC_RELAXED, __HIP_MEMORY_SCOPE_AGENT);
}
__device__ __forceinline__ unsigned long long gldu64(const unsigned long long* p) {
  return __hip_atomic_load(p, __ATOMIC_RELAXED, __HIP_MEMORY_SCOPE_AGENT);
}
__device__ __forceinline__ void gstu64(unsigned long long* p, unsigned long long v) {
  __hip_atomic_store(p, v, __ATOMIC_RELAXED, __HIP_MEMORY_SCOPE_AGENT);
}

// ---- init: zero barrier stripes/release/ccnt/z/ifc/po (plain launch) ------
__global__ void k_init(float* __restrict__ ws) {
  int t = blockIdx.x * 1024 + threadIdx.x;
  if (t < WS_ZERO_WORDS) ws[t] = 0.f;
}

// ---- grid barrier v2: striped arrivals + broadcast release.
// Arrivals: 8 counters on separate 128B lines (<=64 RMWs each, no read flood).
// Block 0 polls the counters (reads) and publishes epoch to a separate release
// line; 511 blocks poll release read-only at low rate (s_sleep(8) ~ 213ns).
// This keeps RMW lines and polled lines disjoint — the round-3 barrier had
// 512 RMWs + 2G polls/s on ONE line (~34us/barrier, coherent-point serialization).
__device__ __forceinline__ void gbar(unsigned* bars, unsigned* rel,
                                     unsigned ep, unsigned grid) {
  asm volatile("s_waitcnt vmcnt(0) lgkmcnt(0)" ::: "memory");  // drain stores/atomics
  __syncthreads();                                             // whole block drained
  if (threadIdx.x == 0) {
    __hip_atomic_fetch_add(bars + (blockIdx.x & 7) * 32, 1u,
                           __ATOMIC_RELAXED, __HIP_MEMORY_SCOPE_AGENT);
    if (blockIdx.x == 0) {
      for (;;) {
        unsigned s = 0;
        #pragma unroll
        for (int q = 0; q < 8; ++q)
          s += __hip_atomic_load(bars + q * 32, __ATOMIC_RELAXED, __HIP_MEMORY_SCOPE_AGENT);
        if (s >= ep * grid) break;
        __builtin_amdgcn_s_sleep(1);
      }
      __hip_atomic_store(rel, ep, __ATOMIC_RELAXED, __HIP_MEMORY_SCOPE_AGENT);
    } else {
      while (__hip_atomic_load(rel, __ATOMIC_RELAXED, __HIP_MEMORY_SCOPE_AGENT) < ep)
        __builtin_amdgcn_s_sleep(8);
    }
  }
  __syncthreads();
}

__global__ __launch_bounds__(512, 4) void k_fused(
    const float* __restrict__ x,  const float* __restrict__ dk,
    const float* __restrict__ db, const float* __restrict__ lk,
    const float* __restrict__ lr, const float* __restrict__ lb,
    const float* __restrict__ h0, const float* __restrict__ c0,
    const float* __restrict__ rv, const float* __restrict__ Wo,
    const float* __restrict__ Wi, const float* __restrict__ M,
    const float* __restrict__ us, float* __restrict__ out,
    float* __restrict__ ws)
{
  const unsigned T   = gridDim.x * blockDim.x;
  const unsigned tid = blockIdx.x * blockDim.x + threadIdx.x;
  unsigned* bars = (unsigned*)(ws + OFF_BARS);
  unsigned* rel  = (unsigned*)(ws + OFF_REL);
  unsigned* ccnt = (unsigned*)(ws + OFF_CCNT);
  float* ifc     = ws + OFF_IFC;
  float* po      = ws + OFF_PO;
  float* bsum    = ws + OFF_BSUM;
  float* scores  = ws + OFF_SCORES;
  unsigned long long* cand = (unsigned long long*)(ws + OFF_CAND);
  unsigned ep = 0;

  __shared__ float sh[CD];          // h, per-block replica
  __shared__ float scc[CD];         // c, per-block replica
  __shared__ float sxw[512];        // xw partials, then xw in [0:128)
  __shared__ float s_rk[RR * WC];
  __shared__ float s_wk[WC];
  __shared__ float swred[8][5];
  __shared__ float ssum[5];
  __shared__ unsigned long long sc[CMAX];
  __shared__ unsigned long long srt[CMAX];
  __shared__ float cpe[200];

  // ---- init: h0/c0 -> LDS; xw = x@dense+bias computed redundantly per block
  for (int t = threadIdx.x; t < CD; t += 512) { sh[t] = h0[t]; scc[t] = c0[t]; }
  {
    int j = threadIdx.x & (WC - 1), kc = threadIdx.x >> 7;   // 4 k-chunks x 128
    const float* col = dk + j;
    float a = 0.f;
    int k0 = kc * 128;
    #pragma unroll 8
    for (int k = k0; k < k0 + 128; ++k) a = fmaf(x[k], col[(size_t)k * WC], a);
    sxw[threadIdx.x] = a;
  }
  __syncthreads();
  {
    float v = 0.f;
    if (threadIdx.x < WC)
      v = db[threadIdx.x] + sxw[threadIdx.x] + sxw[threadIdx.x + 128] +
          sxw[threadIdx.x + 256] + sxw[threadIdx.x + 384];
    __syncthreads();
    if (threadIdx.x < WC) sxw[threadIdx.x] = v;
    __syncthreads();
  }

  // ---- LSTM: 5 steps. One barrier per step; gates redundant per block. -----
  // z_s buffers pre-zeroed by k_init; bias folded into gates.
  for (int step = 0; step < 5; ++step) {
    float* zs = ws + OFF_Z + step * C4;
    for (unsigned task = tid; task < (unsigned)(ZCH * C4); task += T) {
      int ch = task / C4;
      int j  = task - ch * C4;
      float acc = 0.f;
      if (ch < ZCHW) {
        int k0 = ch * 32, k1 = (ch == ZCHW - 1) ? CD : k0 + 32;
        const float* col = lr + j;
        #pragma unroll 8
        for (int k = k0; k < k1; ++k) acc = fmaf(sh[k], col[(size_t)k * C4], acc);
      } else {
        int k0 = (ch - ZCHW) * 32;
        const float* col = lk + j;
        if (step == 0) {
          #pragma unroll 8
          for (int k = k0; k < k0 + 32; ++k) acc = fmaf(sxw[k], col[(size_t)k * C4], acc);
        } else {
          const float* xt = rv + (step - 1) * WC;
          #pragma unroll 8
          for (int k = k0; k < k0 + 32; ++k) acc = fmaf(xt[k], col[(size_t)k * C4], acc);
        }
      }
      atomicAdd(&zs[j], acc);   // device-scope: lands at coherent point
    }
    ++ep; gbar(bars, rel, ep, gridDim.x);
    // gates: every block redundantly, z via agent loads, h/c stay in LDS
    for (int j = threadIdx.x; j < CD; j += 512) {
      float zi = gldf(zs + j)          + lb[j];
      float zf = gldf(zs + CD + j)     + lb[CD + j];
      float zg = gldf(zs + 2 * CD + j) + lb[2 * CD + j];
      float zo = gldf(zs + 3 * CD + j) + lb[3 * CD + j];
      float cn = sigm(zf) * scc[j] + sigm(zi) * tanhf(zg);
      scc[j] = cn;
      sh[j]  = sigm(zo) * tanhf(cn);
    }
    __syncthreads();
  }

  // ---- projection: split-K, atomicAdd into po (out) / ifc ------------------
  for (unsigned task = tid; task < (unsigned)(PKT * PROJ_J); task += T) {
    int kt = task / PROJ_J;
    int j  = task - kt * PROJ_J;
    const float* col; int stride; float* dst;
    if (j < OUTD) { col = Wo + j; stride = OUTD; dst = po + j; }
    else { col = Wi + (j - OUTD); stride = IFACED; dst = ifc + (j - OUTD); }
    int k0 = kt * 30, k1 = k0 + 30; if (k1 > CD) k1 = CD;
    float acc = 0.f;
    #pragma unroll 6
    for (int k = k0; k < k1; ++k) acc = fmaf(sh[k], col[(size_t)k * stride], acc);
    atomicAdd(dst, acc);
  }
  ++ep; gbar(bars, rel, ep, gridDim.x);

  // ---- block 0 copies po -> out[0:512]; all blocks normalize keys ----------
  if (blockIdx.x == 0) out[threadIdx.x] = gldf(po + threadIdx.x);
  if (threadIdx.x < 320) {
    int w = threadIdx.x >> 6, lane = threadIdx.x & 63;
    float beta = 1.f + softplusf((w < 4) ? gldf(ifc + RR * WC + w)
                                         : gldf(ifc + RR * WC + RR + WC));
    const float* src = (w < 4) ? (ifc + w * WC) : (ifc + RR * WC + RR);
    float v0 = gldf(src + lane), v1 = gldf(src + lane + 64);
    float sq = v0 * v0 + v1 * v1;
    for (int off = 1; off < 64; off <<= 1) sq += __shfl_xor(sq, off);
    float rn = rsqrtf(fmaxf(sq, 1e-12f)) * beta;
    float* dstp = (w < 4) ? (s_rk + w * WC) : s_wk;
    dstp[lane] = v0 * rn; dstp[lane + 64] = v1 * rn;
  }
  __syncthreads();

  // ---- scores: one row per thread, keys from LDS; block partial sums -------
  float p0 = 0, p1 = 0, p2 = 0, p3 = 0, p4 = 0;
  {
    const float4* K0 = (const float4*)(s_rk);
    const float4* K1 = (const float4*)(s_rk + WC);
    const float4* K2 = (const float4*)(s_rk + 2 * WC);
    const float4* K3 = (const float4*)(s_rk + 3 * WC);
    const float4* KW = (const float4*)(s_wk);
    for (unsigned i = tid; i < NN; i += T) {
      const float4* rowp = (const float4*)(M + (size_t)i * WC);
      float a0 = 0, a1 = 0, a2 = 0, a3 = 0, a4 = 0, sq = 0;
      #pragma unroll 4
      for (int k = 0; k < 32; ++k) {
        float4 m = rowp[k];
        float4 c0v = K0[k], c1v = K1[k], c2v = K2[k], c3v = K3[k], cwv = KW[k];
        sq = fmaf(m.x, m.x, fmaf(m.y, m.y, fmaf(m.z, m.z, fmaf(m.w, m.w, sq))));
        a0 = fmaf(m.x, c0v.x, fmaf(m.y, c0v.y, fmaf(m.z, c0v.z, fmaf(m.w, c0v.w, a0))));
        a1 = fmaf(m.x, c1v.x, fmaf(m.y, c1v.y, fmaf(m.z, c1v.z, fmaf(m.w, c1v.w, a1))));
        a2 = fmaf(m.x, c2v.x, fmaf(m.y, c2v.y, fmaf(m.z, c2v.z, fmaf(m.w, c2v.w, a2))));
        a3 = fmaf(m.x, c3v.x, fmaf(m.y, c3v.y, fmaf(m.z, c3v.z, fmaf(m.w, c3v.w, a3))));
        a4 = fmaf(m.x, cwv.x, fmaf(m.y, cwv.y, fmaf(m.z, cwv.z, fmaf(m.w, cwv.w, a4))));
      }
      float rn = rsqrtf(fmaxf(sq, 1e-12f));
      float e0 = expf(a0 * rn), e1 = expf(a1 * rn), e2 = expf(a2 * rn),
            e3 = expf(a3 * rn), e4 = expf(a4 * rn);
      // plain stores: re-read by the SAME thread after the barrier (own L1/L2)
      scores[0 * (size_t)NN + i] = e0;
      scores[1 * (size_t)NN + i] = e1;
      scores[2 * (size_t)NN + i] = e2;
      scores[3 * (size_t)NN + i] = e3;
      scores[4 * (size_t)NN + i] = e4;
      p0 += e0; p1 += e1; p2 += e2; p3 += e3; p4 += e4;
    }
  }
  {
    for (int off = 1; off < 64; off <<= 1) {
      p0 += __shfl_xor(p0, off); p1 += __shfl_xor(p1, off); p2 += __shfl_xor(p2, off);
      p3 += __shfl_xor(p3, off); p4 += __shfl_xor(p4, off);
    }
    int wv = threadIdx.x >> 6, ln = threadIdx.x & 63;
    if (ln == 0) { swred[wv][0] = p0; swred[wv][1] = p1; swred[wv][2] = p2;
                   swred[wv][3] = p3; swred[wv][4] = p4; }
    __syncthreads();
    if (threadIdx.x < 5) {
      float s = 0.f;
      for (int q = 0; q < 8; ++q) s += swred[q][threadIdx.x];
      gstf(bsum + blockIdx.x * 5 + threadIdx.x, s);
    }
  }
  ++ep; gbar(bars, rel, ep, gridDim.x);

  // ---- totals (redundant per block) + finalize outputs + candidate filter --
  {
    float q0 = 0, q1 = 0, q2 = 0, q3 = 0, q4 = 0;
    for (unsigned t = threadIdx.x; t < gridDim.x; t += 512) {
      const float* bp = bsum + t * 5;
      q0 += gldf(bp); q1 += gldf(bp + 1); q2 += gldf(bp + 2);
      q3 += gldf(bp + 3); q4 += gldf(bp + 4);
    }
    for (int off = 1; off < 64; off <<= 1) {
      q0 += __shfl_xor(q0, off); q1 += __shfl_xor(q1, off); q2 += __shfl_xor(q2, off);
      q3 += __shfl_xor(q3, off); q4 += __shfl_xor(q4, off);
    }
    int wv = threadIdx.x >> 6, ln = threadIdx.x & 63;
    if (ln == 0) { swred[wv][0] = q0; swred[wv][1] = q1; swred[wv][2] = q2;
                   swred[wv][3] = q3; swred[wv][4] = q4; }
    __syncthreads();
    if (threadIdx.x < 5) {
      float s = 0.f;
      for (int q = 0; q < 8; ++q) s += swred[q][threadIdx.x];
      ssum[threadIdx.x] = s;
    }
    __syncthreads();
  }
  {
    float i0 = 1.f / ssum[0], i1 = 1.f / ssum[1], i2 = 1.f / ssum[2],
          i3 = 1.f / ssum[3], i4 = 1.f / ssum[4];
    for (unsigned i = tid; i < NN; i += T) {
      float4 wr;
      wr.x = scores[0 * (size_t)NN + i] * i0;
      wr.y = scores[1 * (size_t)NN + i] * i1;
      wr.z = scores[2 * (size_t)NN + i] * i2;
      wr.w = scores[3 * (size_t)NN + i] * i3;
      *(float4*)(out + OUTD + (size_t)i * 4) = wr;                  // single writer
      out[OUTD + 4 * (size_t)NN + i] = scores[4 * (size_t)NN + i] * i4;
      gstf(out + OUTD + 5 * (size_t)NN + i, 0.f);  // alloc col agent-scope (no dirty L2)
      float u = us[i];
      if (u < 2e-3f) {
        unsigned slot = atomicAdd(ccnt, 1u);
        if (slot < CMAX)
          gstu64(cand + slot, ((unsigned long long)__float_as_uint(u) << 32) | i);
      }
    }
  }
  ++ep; gbar(bars, rel, ep, gridDim.x);

  // ---- alloc: block 0, exact rank-sort of candidates + fp32 cumprod --------
  // cumprod of sorted ascending uniforms underflows after ~10 terms; ranks>=200
  // keep the zero written above (ref values there < 1e-38). Composite keys
  // (u<<32)|i are unique -> ranks are a permutation.
  if (blockIdx.x == 0) {
    int n = (int)gldu(ccnt); if (n > CMAX) n = CMAX;
    for (int t = threadIdx.x; t < n; t += 512) sc[t] = gldu64(cand + t);
    __syncthreads();
    for (int t = threadIdx.x; t < n; t += 512) {
      unsigned long long v = sc[t];
      int r = 0;
      for (int j2 = 0; j2 < n; ++j2) r += (sc[j2] < v);
      srt[r] = v;
    }
    __syncthreads();
    int lim = n < 200 ? n : 200;
    if (threadIdx.x == 0) {
      float cp = 1.f;
      for (int r = 0; r < lim; ++r) {
        cpe[r] = cp;
        cp *= __uint_as_float((unsigned)(srt[r] >> 32));
      }
    }
    __syncthreads();
    for (int r = threadIdx.x; r < lim; r += 512) {
      unsigned long long pr = srt[r];
      float s = __uint_as_float((unsigned)(pr >> 32));
      gstf(out + OUTD + 5 * (size_t)NN + (unsigned)pr, (1.f - s) * cpe[r]);
    }
  }
}

extern "C" void kernel_launch(void* const* d_in, const int* in_sizes, int n_in,
                              void* d_out, int out_size, void* d_ws, size_t ws_size,
                              hipStream_t stream) {
  const float* x  = (const float*)d_in[0];
  const float* dk = (const float*)d_in[1];
  const float* db = (const float*)d_in[2];
  const float* lk = (const float*)d_in[3];
  const float* lr = (const float*)d_in[4];
  const float* lb = (const float*)d_in[5];
  const float* h0 = (const float*)d_in[6];
  const float* c0 = (const float*)d_in[7];
  const float* rv = (const float*)d_in[8];
  const float* Wo = (const float*)d_in[9];
  const float* Wi = (const float*)d_in[10];
  const float* M  = (const float*)d_in[11];
  const float* us = (const float*)d_in[12];
  float* out = (float*)d_out;
  float* ws  = (float*)d_ws;

  static int grid = 0;
  if (grid == 0) {
    int nb = 0;
    if (hipOccupancyMaxActiveBlocksPerMultiprocessor(&nb, (const void*)k_fused, 512, 0) != hipSuccess || nb < 1)
      nb = 1;
    long g = (long)nb * 256;        // 256 CUs
    grid = (int)(g < 512 ? g : 512);
  }

  // zero barrier stripes/release, ccnt, z[5], ifc, po — plain kernel
  k_init<<<(WS_ZERO_WORDS + 1023) / 1024, 1024, 0, stream>>>(ws);

  void* args[] = { &x, &dk, &db, &lk, &lr, &lb, &h0, &c0, &rv,
                   &Wo, &Wi, &M, &us, &out, &ws };
  hipLaunchCooperativeKernel((const void*)k_fused, dim3(grid), dim3(512),
                             args, 0, stream);
}